// Round 6
// baseline (128.518 us; speedup 1.0000x reference)
//
#include <hip/hip_runtime.h>

// LSTM classifier single step: B=65536, IN=64, H=128, OUT=2.
// Harness facts (R0-R5): 256 MiB d_ws re-poison fill + input restores are
// harness-fixed ~94us/iter — d_ws use is free. lstm trajectory: 52 (R1) ->
// 40 (R3, coalesced c0) -> ~28 (R4, pre-built bf16 frags). Occupancy is NOT
// the limiter (R5: 16 waves/CU neutral). R6 theory: compiler's vmcnt(0)
// drain before each s_barrier made the per-iter prefetch synchronous (loads
// issued right before barrier). T14 fix: issue loads at iter START, stage
// regs->LDS at iter END, barrier last -> latency hidden under compute.
// Also: exp2 scale constants folded into frags/bias (prep), shfl reduce
// trimmed 4->2 steps (4 partials folded in final phase).

#define B_SIZE 65536

typedef __bf16 bf16x8 __attribute__((ext_vector_type(8)));
typedef __bf16 bf16x4 __attribute__((ext_vector_type(4)));
typedef float f32x4 __attribute__((ext_vector_type(4)));

#define LOG2E 1.442695040888963f
#define TWO_LOG2E 2.885390081777927f

// Full tanh (for h = o*tanh(c), c computed at runtime, can't prescale)
__device__ __forceinline__ float ftanh(float x) {
    float e = __builtin_amdgcn_exp2f(TWO_LOG2E * x);
    return 1.0f - 2.0f * __builtin_amdgcn_rcpf(e + 1.0f);
}

// blocks 0..7:  bias512[g*128+r] = scale_g * (bx_g[r] + h0 @ Wh_g[r,:])
// blocks 8..71: frags[t*8+j] = bf16(scale_g * Wx_g[...]), MFMA B-frag layout,
//               t = w*1024 + g*256 + cb*128 + kb*64 + lane.
// scale_g = -log2(e) for f,i,o (sigmoid) ; +2*log2(e) for c (tanh) — folds
// the exp2 argument scaling into the matmul.
__global__ void prep_kernel(const float* __restrict__ h0,
                            const float* __restrict__ Whf, const float* __restrict__ Whi,
                            const float* __restrict__ Who, const float* __restrict__ Whc,
                            const float* __restrict__ bxf, const float* __restrict__ bxi,
                            const float* __restrict__ bxo, const float* __restrict__ bxc,
                            const float* __restrict__ Wxf, const float* __restrict__ Wxi,
                            const float* __restrict__ Wxo, const float* __restrict__ Wxc,
                            float* __restrict__ bias512, __bf16* __restrict__ frags) {
    if (blockIdx.x < 8) {
        int j = blockIdx.x * 64 + threadIdx.x;   // 512 bias entries
        int g = j >> 7, r = j & 127;
        const float* Wh = (g == 0) ? Whf : (g == 1) ? Whi : (g == 2) ? Who : Whc;
        const float* bx = (g == 0) ? bxf : (g == 1) ? bxi : (g == 2) ? bxo : bxc;
        const float sg = (g == 3) ? TWO_LOG2E : -LOG2E;
        float s = bx[r];
        const float4* row = (const float4*)(Wh + r * 128);
        const float4* h4  = (const float4*)h0;
#pragma unroll 8
        for (int k = 0; k < 32; ++k) {
            float4 a = row[k], b = h4[k];
            s += a.x * b.x + a.y * b.y + a.z * b.z + a.w * b.w;
        }
        bias512[j] = s * sg;
    } else {
        int t = (blockIdx.x - 8) * 64 + threadIdx.x;   // 4096 fragment slots
        int w    = t >> 10;
        int g    = (t >> 8) & 3;
        int cb   = (t >> 7) & 1;
        int kb   = (t >> 6) & 1;
        int lane = t & 63;
        const float* Wx = (g == 0) ? Wxf : (g == 1) ? Wxi : (g == 2) ? Wxo : Wxc;
        const float sg = (g == 3) ? TWO_LOG2E : -LOG2E;
        const int n = w * 32 + cb * 16 + (lane & 15);
        const float* p = Wx + n * 64 + kb * 32 + (lane >> 4) * 8;
        float4 lo = *(const float4*)p;
        float4 hi = *(const float4*)(p + 4);
        bf16x8 v;
        v[0] = (__bf16)(lo.x * sg); v[1] = (__bf16)(lo.y * sg);
        v[2] = (__bf16)(lo.z * sg); v[3] = (__bf16)(lo.w * sg);
        v[4] = (__bf16)(hi.x * sg); v[5] = (__bf16)(hi.y * sg);
        v[6] = (__bf16)(hi.z * sg); v[7] = (__bf16)(hi.w * sg);
        *(bf16x8*)(frags + (size_t)t * 8) = v;
    }
}

__launch_bounds__(256, 2)
__global__ void lstm_kernel(const float* __restrict__ x, const float* __restrict__ c0,
                            const __bf16* __restrict__ frags,
                            const float* __restrict__ Wy, const float* __restrict__ by,
                            const float* __restrict__ bias512, float* __restrict__ out) {
    __shared__ __bf16 xs[2][1024];       // 16 rows x 64 k of x, A-fragment layout
    __shared__ float cs[2][16 * 132];    // 16 rows x 128 cols of c0, +4 pad/row
    __shared__ float yred[4][128][8];    // [wave][block row][o*4 + partial]

    const int tid  = threadIdx.x;
    const int lane = tid & 63;
    const int w    = tid >> 6;           // wave 0..3 -> hidden cols [w*32, w*32+32)
    const int q    = lane >> 4;          // quad: rows q*4..q*4+3 of the 16-row tile
    const int n15  = lane & 15;          // col within 16-col tile

    // ---- prologue: pre-built (pre-scaled) bf16 fragments, coalesced loads ----
    bf16x8 bw[4][2][2];                  // [gate][colblock][kstep]
    float biasv[4][2];
#pragma unroll
    for (int g = 0; g < 4; ++g)
#pragma unroll
        for (int cb = 0; cb < 2; ++cb) {
            biasv[g][cb] = bias512[g * 128 + w * 32 + cb * 16 + n15];
#pragma unroll
            for (int kb = 0; kb < 2; ++kb)
                bw[g][cb][kb] = *(const bf16x8*)(frags +
                    (size_t)(((w * 16 + g * 4 + cb * 2 + kb) * 64 + lane)) * 8);
        }
    float wyv[2][2];
#pragma unroll
    for (int o = 0; o < 2; ++o)
#pragma unroll
        for (int cb = 0; cb < 2; ++cb)
            wyv[o][cb] = Wy[o * 128 + w * 32 + cb * 16 + n15];
    const float by0 = by[0], by1 = by[1];

    constexpr int ITERS = (B_SIZE / 16) / 512;   // 8 tiles of 16 rows per block
    const int tile0 = blockIdx.x * ITERS;        // contiguous 128 rows per block

    // x staging: thread t loads float4 of row (t>>4), k4=(t&15)*4 ; LDS index in
    // A-frag order: elem(m,k) -> (k>>5)*512 + ((k&31)>>3)*128 + m*8 + (k&7)
    const int xrow = tid >> 4;
    const int k4   = (tid & 15) * 4;
    const int sidx = (k4 >> 5) * 512 + ((k4 & 31) >> 3) * 128 + xrow * 8 + (k4 & 7);

    // c0 staging: thread t loads 8 consecutive floats of row (t>>4), cols (t&15)*8
    const int ccol = (tid & 15) * 8;
    const int cidx = xrow * 132 + ccol;

    // Two prefetch register sets, ping-pong (all indices static after unroll).
    float4 xr[2], cpa[2], cpb[2];

    // ---- prologue: tile0 -> set0 -> buf0; reload set0 <- tile1 ----
    xr[0]  = *(const float4*)(x  + (size_t)(tile0 * 16 + xrow) * 64 + k4);
    cpa[0] = *(const float4*)(c0 + (size_t)(tile0 * 16 + xrow) * 128 + ccol);
    cpb[0] = *(const float4*)(c0 + (size_t)(tile0 * 16 + xrow) * 128 + ccol + 4);
    {
        bf16x4 v; v[0] = (__bf16)xr[0].x; v[1] = (__bf16)xr[0].y;
        v[2] = (__bf16)xr[0].z; v[3] = (__bf16)xr[0].w;
        *(bf16x4*)&xs[0][sidx] = v;
        *(float4*)&cs[0][cidx] = cpa[0];
        *(float4*)&cs[0][cidx + 4] = cpb[0];
    }
    xr[0]  = *(const float4*)(x  + (size_t)((tile0 + 1) * 16 + xrow) * 64 + k4);
    cpa[0] = *(const float4*)(c0 + (size_t)((tile0 + 1) * 16 + xrow) * 128 + ccol);
    cpb[0] = *(const float4*)(c0 + (size_t)((tile0 + 1) * 16 + xrow) * 128 + ccol + 4);
    __syncthreads();

#pragma unroll
    for (int it = 0; it < ITERS; ++it) {
        const int cur = it & 1;      // LDS buffer holding tile `it`
        const int hs  = it & 1;      // reg set holding tile it+1 (staged at end)
        const int fs  = hs ^ 1;      // reg set receiving tile it+2 (issued now)

        // (1) ISSUE loads for tile it+2 FIRST — vmcnt(0) at the barrier then
        //     lands a full compute phase later (T14 issue-early).
        if (it + 2 < ITERS) {
            const int tn = tile0 + it + 2;
            xr[fs]  = *(const float4*)(x  + (size_t)(tn * 16 + xrow) * 64 + k4);
            cpa[fs] = *(const float4*)(c0 + (size_t)(tn * 16 + xrow) * 128 + ccol);
            cpb[fs] = *(const float4*)(c0 + (size_t)(tn * 16 + xrow) * 128 + ccol + 4);
        }

        // (2) compute tile `it` from LDS buf `cur`
        bf16x8 a0 = *(const bf16x8*)&xs[cur][lane * 8];
        bf16x8 a1 = *(const bf16x8*)&xs[cur][512 + lane * 8];

        float c0v[2][4];
#pragma unroll
        for (int cb = 0; cb < 2; ++cb)
#pragma unroll
            for (int r = 0; r < 4; ++r)
                c0v[cb][r] = cs[cur][(q * 4 + r) * 132 + w * 32 + cb * 16 + n15];

        f32x4 acc[4][2];
#pragma unroll
        for (int g = 0; g < 4; ++g)
#pragma unroll
            for (int cb = 0; cb < 2; ++cb) {
                float b = biasv[g][cb];
                f32x4 t = {b, b, b, b};
                acc[g][cb] = t;
            }
#pragma unroll
        for (int g = 0; g < 4; ++g)
#pragma unroll
            for (int cb = 0; cb < 2; ++cb) {
                acc[g][cb] = __builtin_amdgcn_mfma_f32_16x16x32_bf16(a0, bw[g][cb][0], acc[g][cb], 0, 0, 0);
                acc[g][cb] = __builtin_amdgcn_mfma_f32_16x16x32_bf16(a1, bw[g][cb][1], acc[g][cb], 0, 0, 0);
            }

        // elementwise epilogue; scales pre-folded into acc (prep_kernel):
        // sigmoid(z) = rcp(1+exp2(acc)), tanh(z) = 1-2*rcp(exp2(acc)+1)
        float p0[4] = {0.f, 0.f, 0.f, 0.f};
        float p1[4] = {0.f, 0.f, 0.f, 0.f};
#pragma unroll
        for (int cb = 0; cb < 2; ++cb)
#pragma unroll
            for (int r = 0; r < 4; ++r) {
                float fg = __builtin_amdgcn_rcpf(1.0f + __builtin_amdgcn_exp2f(acc[0][cb][r]));
                float ig = __builtin_amdgcn_rcpf(1.0f + __builtin_amdgcn_exp2f(acc[1][cb][r]));
                float og = __builtin_amdgcn_rcpf(1.0f + __builtin_amdgcn_exp2f(acc[2][cb][r]));
                float ec = __builtin_amdgcn_exp2f(acc[3][cb][r]);
                float ct = 1.0f - 2.0f * __builtin_amdgcn_rcpf(ec + 1.0f);
                float c  = fg * c0v[cb][r] + ig * ct;
                float h  = og * ftanh(c);
                p0[r] += h * wyv[0][cb];
                p1[r] += h * wyv[1][cb];
            }
        // 2-step reduce (16 lanes -> 4 partials); partials folded at the end
#pragma unroll
        for (int m = 1; m < 4; m <<= 1) {
#pragma unroll
            for (int r = 0; r < 4; ++r) {
                p0[r] += __shfl_xor(p0[r], m, 64);
                p1[r] += __shfl_xor(p1[r], m, 64);
            }
        }
        if ((n15 & 3) == 0) {
            const int part = n15 >> 2;
#pragma unroll
            for (int r = 0; r < 4; ++r) {
                yred[w][it * 16 + q * 4 + r][part]     = p0[r];
                yred[w][it * 16 + q * 4 + r][4 + part] = p1[r];
            }
        }

        // (3) STAGE tile it+1 (regs, loaded last iter) into the other buffer
        if (it + 1 < ITERS) {
            bf16x4 v; v[0] = (__bf16)xr[hs].x; v[1] = (__bf16)xr[hs].y;
            v[2] = (__bf16)xr[hs].z; v[3] = (__bf16)xr[hs].w;
            *(bf16x4*)&xs[cur ^ 1][sidx] = v;
            *(float4*)&cs[cur ^ 1][cidx] = cpa[hs];
            *(float4*)&cs[cur ^ 1][cidx + 4] = cpb[hs];
        }
        __syncthreads();
    }

    // ---- final out phase: 128 contiguous rows, coalesced float2 stores ----
    if (tid < 128) {
        float s0 = by0, s1 = by1;
#pragma unroll
        for (int w2 = 0; w2 < 4; ++w2)
#pragma unroll
            for (int p = 0; p < 4; ++p) {
                s0 += yred[w2][tid][p];
                s1 += yred[w2][tid][4 + p];
            }
        float2 s = {s0, s1};
        *(float2*)(out + (size_t)(tile0 * 16 + tid) * 2) = s;
    }
}

extern "C" void kernel_launch(void* const* d_in, const int* in_sizes, int n_in,
                              void* d_out, int out_size, void* d_ws, size_t ws_size,
                              hipStream_t stream) {
    // setup_inputs order: x, h0, c0, [Wxf,bxf,Whf], [Wxi,bxi,Whi], [Wxo,bxo,Who],
    //                     [Wxc,bxc,Whc], Wy, by
    const float* x   = (const float*)d_in[0];
    const float* h0  = (const float*)d_in[1];
    const float* c0  = (const float*)d_in[2];
    const float* Wxf = (const float*)d_in[3];
    const float* bxf = (const float*)d_in[4];
    const float* Whf = (const float*)d_in[5];
    const float* Wxi = (const float*)d_in[6];
    const float* bxi = (const float*)d_in[7];
    const float* Whi = (const float*)d_in[8];
    const float* Wxo = (const float*)d_in[9];
    const float* bxo = (const float*)d_in[10];
    const float* Who = (const float*)d_in[11];
    const float* Wxc = (const float*)d_in[12];
    const float* bxc = (const float*)d_in[13];
    const float* Whc = (const float*)d_in[14];
    const float* Wy  = (const float*)d_in[15];
    const float* by  = (const float*)d_in[16];
    float* out = (float*)d_out;
    float* bias512 = (float*)d_ws;                   // 512 floats
    __bf16* frags  = (__bf16*)((float*)d_ws + 512);  // 4096 x bf16x8 = 64 KB

    prep_kernel<<<72, 64, 0, stream>>>(h0, Whf, Whi, Who, Whc, bxf, bxi, bxo, bxc,
                                       Wxf, Wxi, Wxo, Wxc, bias512, frags);
    lstm_kernel<<<512, 256, 0, stream>>>(x, c0, frags, Wy, by, bias512, out);
}